// Round 3
// baseline (372.642 us; speedup 1.0000x reference)
//
#include <hip/hip_runtime.h>
#include <hip/hip_bf16.h>
#include <hip/hip_fp16.h>

typedef _Float16 f16;
typedef _Float16 f16x8 __attribute__((ext_vector_type(8)));
typedef _Float16 f16x4 __attribute__((ext_vector_type(4)));
typedef float f32x4 __attribute__((ext_vector_type(4)));
typedef float f32x16 __attribute__((ext_vector_type(16)));

#define NP   4096   // H*W
#define NB   8      // batch
#define CINC 256    // input channels
#define EMB  128
#define OUTC 256
#define BN_EPS 1e-5f

#define DSZ  ((size_t)NB * NP * EMB)      // 4194304 halves, per-dir tensor
#define TSZ  (2 * DSZ)                    // 8388608 halves

// =======================================================================
// Kernel 1: ALL 6 input projections in one launch. grid (32, 6, 8).
//   p = blockIdx.y: 0..2 = rgb stream (q_rgb,k_rgb,v_rgb), 3..5 = pl stream.
//   j = p%3: 0 -> Q[s] ([b][n][128]) ; 1 -> K[1-s] ; 2 -> V[1-s] ([b][d][4096])
// =======================================================================
__global__ __launch_bounds__(256) void proj_all_kernel(
    const float* __restrict__ Xrgb, const float* __restrict__ Xpl,
    const float* __restrict__ w0, const float* __restrict__ b0,
    const float* __restrict__ w1, const float* __restrict__ b1,
    const float* __restrict__ w2, const float* __restrict__ b2,
    const float* __restrict__ w3, const float* __restrict__ b3,
    const float* __restrict__ w4, const float* __restrict__ b4,
    const float* __restrict__ w5, const float* __restrict__ b5,
    f16* __restrict__ Qt, f16* __restrict__ Kt, f16* __restrict__ Vn)
{
    const int m0 = blockIdx.x * 128;
    const int p  = blockIdx.y;
    const int b  = blockIdx.z;
    const int s  = (p >= 3) ? 1 : 0;
    const int j  = p - s * 3;
    const int tid = threadIdx.x;
    const int w = tid >> 6, lane = tid & 63, quad = lane >> 4, lr = lane & 15;

    const float* X  = s ? Xpl : Xrgb;
    const float* W  = p == 0 ? w0 : p == 1 ? w1 : p == 2 ? w2
                    : p == 3 ? w3 : p == 4 ? w4 : w5;
    const float* Bi = p == 0 ? b0 : p == 1 ? b1 : p == 2 ? b2
                    : p == 3 ? b3 : p == 4 ? b4 : b5;

    __shared__ __align__(16) f16 smem[128 * 72 * 2];   // 36864 B
    f16* Al = smem;             // [128 n][72]
    f16* Bl = smem + 128 * 72;  // [128 d][72]

    f32x4 acc[2][8];
    #pragma unroll
    for (int mi = 0; mi < 2; ++mi)
        #pragma unroll
        for (int ni = 0; ni < 8; ++ni) acc[mi][ni] = (f32x4){0.f, 0.f, 0.f, 0.f};

    for (int kt = 0; kt < 4; ++kt) {
        const int kc0 = kt * 64;
        __syncthreads();
        // A: X[c][n] -> Al[n][c] (transpose + convert); lanes coalesced over n
        for (int s2 = tid; s2 < 1024; s2 += 256) {
            const int n = s2 & 127, cg = s2 >> 7;
            f16 tmp[8];
            #pragma unroll
            for (int jj = 0; jj < 8; ++jj)
                tmp[jj] = (f16)X[((size_t)b * CINC + kc0 + cg * 8 + jj) * NP + m0 + n];
            *(f16x8*)&Al[n * 72 + cg * 8] = *(const f16x8*)tmp;
        }
        // B: W[d][c] contiguous fp32 -> convert
        for (int s2 = tid; s2 < 1024; s2 += 256) {
            const int d = s2 >> 3, cg = s2 & 7;
            f16 tmp[8];
            #pragma unroll
            for (int jj = 0; jj < 8; ++jj)
                tmp[jj] = (f16)W[(size_t)d * CINC + kc0 + cg * 8 + jj];
            *(f16x8*)&Bl[d * 72 + cg * 8] = *(const f16x8*)tmp;
        }
        __syncthreads();
        #pragma unroll
        for (int ks = 0; ks < 2; ++ks) {
            f16x8 af[2], bfr[8];
            #pragma unroll
            for (int mi = 0; mi < 2; ++mi)
                af[mi] = *(const f16x8*)&Al[(w * 32 + mi * 16 + lr) * 72 + ks * 32 + quad * 8];
            #pragma unroll
            for (int ni = 0; ni < 8; ++ni)
                bfr[ni] = *(const f16x8*)&Bl[(ni * 16 + lr) * 72 + ks * 32 + quad * 8];
            #pragma unroll
            for (int mi = 0; mi < 2; ++mi)
                #pragma unroll
                for (int ni = 0; ni < 8; ++ni)
                    acc[mi][ni] = __builtin_amdgcn_mfma_f32_16x16x32_f16(
                        af[mi], bfr[ni], acc[mi][ni], 0, 0, 0);
        }
    }

    float bias[8];
    #pragma unroll
    for (int ni = 0; ni < 8; ++ni) bias[ni] = Bi[ni * 16 + lr];

    if (j < 2) {
        f16* out = (j == 0) ? (Qt + (size_t)s * DSZ) : (Kt + (size_t)(1 - s) * DSZ);
        #pragma unroll
        for (int mi = 0; mi < 2; ++mi)
            #pragma unroll
            for (int ni = 0; ni < 8; ++ni)
                #pragma unroll
                for (int r = 0; r < 4; ++r) {
                    const int n = m0 + w * 32 + mi * 16 + quad * 4 + r;
                    out[((size_t)b * NP + n) * EMB + ni * 16 + lr] =
                        (f16)(acc[mi][ni][r] + bias[ni]);
                }
    } else {
        f16* outV = Vn + (size_t)(1 - s) * DSZ;
        __syncthreads();
        f16* T = smem;                        // [128 d][136]
        #pragma unroll
        for (int mi = 0; mi < 2; ++mi)
            #pragma unroll
            for (int ni = 0; ni < 8; ++ni)
                #pragma unroll
                for (int r = 0; r < 4; ++r)
                    T[(ni * 16 + lr) * 136 + w * 32 + mi * 16 + quad * 4 + r] =
                        (f16)(acc[mi][ni][r] + bias[ni]);
        __syncthreads();
        for (int s2 = tid; s2 < 2048; s2 += 256) {
            const int d = s2 >> 4, n8 = (s2 & 15) * 8;
            *(f16x8*)&outV[((size_t)b * EMB + d) * NP + m0 + n8] =
                *(const f16x8*)&T[d * 136 + n8];
        }
    }
}

// =======================================================================
// Kernel 2: flash attention, 32x32x16 MFMA structure.
//  - 4 waves/block, 64 q/wave (2 q32-blocks), 256 q/block. grid = 256
//    (16 n-blocks x 16 (dir,b)); bid&15 keeps each (dir,b)'s 16 blocks on
//    one XCD (K/V L2-resident).
//  - S^T = mfma_32x32x16(A=K, B=Q) -> exp2 in-register -> P rebuilt into
//    the PV B-operand via __shfl_xor(x,32) cross-half exchange (semantics
//    unambiguous; permlane asm caused round-1/2 failures).
//  - PV: O^T[d][q] = mfma_32x32x16(A=V[d][key], B=P^T) -- full-rate.
//  - K/V tiles double-buffered in LDS, XOR chunk-swizzle (c ^= row&7) on
//    write+read -> conflict-free ds_read_b128 / ds_write_b128.
//  - T14 split staging: global loads issued right after the barrier,
//    ds_writes after compute.
// =======================================================================
__device__ __forceinline__ unsigned pkf16(float a, float b) {
    union { f16 h[2]; unsigned u; } t;
    t.h[0] = (f16)a; t.h[1] = (f16)b;
    return t.u;
}

__global__ __launch_bounds__(256, 1) void attn_kernel(
    const f16* __restrict__ Qt, const f16* __restrict__ Kt,
    const f16* __restrict__ Vn, f16* __restrict__ combT)
{
    const int bid = blockIdx.x;
    const int g = bid & 15, dir = g >> 3, b = g & 7;
    const int n0 = (bid >> 4) * 256;
    const int tid = threadIdx.x;
    const int w = tid >> 6, lane = tid & 63;
    const int l31 = lane & 31, hi = lane >> 5;

    const f16* __restrict__ Q = Qt + ((size_t)dir * NB + b) * NP * EMB;
    const f16* __restrict__ K = Kt + ((size_t)dir * NB + b) * NP * EMB;
    const f16* __restrict__ V = Vn + ((size_t)dir * NB + b) * (size_t)EMB * NP;

    __shared__ __align__(16) f16 Kl[2][64 * 128];    // [key][d], chunk-swizzled
    __shared__ __align__(16) f16 Vl[2][128 * 64];    // [d][key], chunk-swizzled

    const int qbase = n0 + w * 64;

    // Q B-frags: B[k=d=hi*8+j][col=q=l31], scale*log2(e) folded in.
    f16x8 qf[2][8];
    #pragma unroll
    for (int q32 = 0; q32 < 2; ++q32)
        #pragma unroll
        for (int d16 = 0; d16 < 8; ++d16) {
            f16x8 q = *(const f16x8*)&Q[(size_t)(qbase + q32 * 32 + l31) * EMB + d16 * 16 + hi * 8];
            #pragma unroll
            for (int jj = 0; jj < 8; ++jj)
                q[jj] = q[jj] * (f16)0.12752749f;   // 128^-0.5 * log2(e)
            qf[q32][d16] = q;
        }

    f32x16 O[4][2];
    #pragma unroll
    for (int d32 = 0; d32 < 4; ++d32)
        #pragma unroll
        for (int q32 = 0; q32 < 2; ++q32) O[d32][q32] = (f32x16)(0.0f);
    float rs[2] = {0.f, 0.f};

    // staging lane decomposition (constant per thread)
    const int krp = lane >> 4, kp = lane & 15;   // K: 4 rows x 16 chunks per load
    const int vrp = lane >> 3, vp = lane & 7;    // V: 8 rows x 8 chunks per load
    f16x8 stK[4], stV[4];

    auto stage_load = [&](int m0) {
        #pragma unroll
        for (int i = 0; i < 4; ++i) {
            const int r = w * 16 + i * 4 + krp;
            const int c = kp ^ (r & 7);
            stK[i] = *(const f16x8*)&K[(size_t)(m0 + r) * EMB + c * 8];
        }
        #pragma unroll
        for (int i = 0; i < 4; ++i) {
            const int r = w * 32 + i * 8 + vrp;
            const int c = vp ^ (r & 7);
            stV[i] = *(const f16x8*)&V[(size_t)r * NP + m0 + c * 8];
        }
    };
    auto stage_write = [&](int buf) {
        #pragma unroll
        for (int i = 0; i < 4; ++i) {
            const int r = w * 16 + i * 4 + krp;
            *(f16x8*)&Kl[buf][r * 128 + kp * 8] = stK[i];
        }
        #pragma unroll
        for (int i = 0; i < 4; ++i) {
            const int r = w * 32 + i * 8 + vrp;
            *(f16x8*)&Vl[buf][r * 64 + vp * 8] = stV[i];
        }
    };

    stage_load(0);
    stage_write(0);
    int cur = 0;

    for (int t = 0; t < NP / 64; ++t) {
        __syncthreads();                        // buf[cur] ready for all waves
        if (t < NP / 64 - 1) stage_load((t + 1) * 64);

        const f16* Kb = &Kl[cur][0];
        const f16* Vb = &Vl[cur][0];

        #pragma unroll
        for (int k32 = 0; k32 < 2; ++k32) {
            // ---- QK^T (swapped): S^T[key][q] for 32 keys x 64 q ----
            f32x16 s0 = (f32x16)(0.0f), s1 = (f32x16)(0.0f);
            #pragma unroll
            for (int d16 = 0; d16 < 8; ++d16) {
                const int r = k32 * 32 + l31;
                const int c = (d16 * 2 + hi) ^ (r & 7);
                const f16x8 kf = *(const f16x8*)&Kb[r * 128 + c * 8];
                s0 = __builtin_amdgcn_mfma_f32_32x32x16_f16(kf, qf[0][d16], s0, 0, 0, 0);
                s1 = __builtin_amdgcn_mfma_f32_32x32x16_f16(kf, qf[1][d16], s1, 0, 0, 0);
            }

            // ---- exp2 + rowsum + rebuild P^T B-frags in-register ----
            // C-layout: col=q=l31, key=(reg&3)+8*(reg>>2)+4*hi (+16 per reg-octet).
            // Lane holds (per 16-key group g2, local keys): pa=(0,1)+4hi,
            // pbu=(2,3)+4hi, pc=(8,9)+4hi, pd=(10,11)+4hi.
            // B-frag element (hi,j) needs local key hi*8+j. Cross-half
            // exchange via __shfl_xor(.,32):
            //   send = hi ? pa : pc ; recv = partner's send.
            //   lo: dw0=pa(0,1) dw1=pbu(2,3) dw2=recv(=hi-partner pa=(4,5))
            //       dw3=recv1(=(6,7))
            //   hi: dw0=recv(=lo-partner pc=(8,9)) dw1=recv1(=(10,11))
            //       dw2=pc(12,13) dw3=pd(14,15)
            f16x8 pb[2][2];   // [key16-group][q32]
            #pragma unroll
            for (int q32 = 0; q32 < 2; ++q32) {
                const f32x16 s = q32 ? s1 : s0;
                float e[16];
                #pragma unroll
                for (int i = 0; i < 16; ++i) e[i] = __builtin_amdgcn_exp2f(s[i]);
                float sum = 0.f;
                #pragma unroll
                for (int i = 0; i < 16; ++i) sum += e[i];
                rs[q32] += sum;
                #pragma unroll
                for (int g2 = 0; g2 < 2; ++g2) {
                    const unsigned pa  = pkf16(e[g2 * 8 + 0], e[g2 * 8 + 1]);
                    const unsigned pbu = pkf16(e[g2 * 8 + 2], e[g2 * 8 + 3]);
                    const unsigned pc  = pkf16(e[g2 * 8 + 4], e[g2 * 8 + 5]);
                    const unsigned pd  = pkf16(e[g2 * 8 + 6], e[g2 * 8 + 7]);
                    const unsigned recv0 = __shfl_xor(hi ? pa : pc, 32);
                    const unsigned recv1 = __shfl_xor(hi ? pbu : pd, 32);
                    union { unsigned u[4]; f16x8 v; } pu;
                    pu.u[0] = hi ? recv0 : pa;
                    pu.u[1] = hi ? recv1 : pbu;
                    pu.u[2] = hi ? pc : recv0;
                    pu.u[3] = hi ? pd : recv1;
                    pb[g2][q32] = pu.v;
                }
            }

            // ---- PV: O^T[d][q] += V[d][key] . P^T[key][q] (full-rate) ----
            // g2 outer / d32 inner: same-accumulator MFMAs 8 apart (RAW dist).
            #pragma unroll
            for (int g2 = 0; g2 < 2; ++g2) {
                #pragma unroll
                for (int d32 = 0; d32 < 4; ++d32) {
                    const int r = d32 * 32 + l31;
                    const int c = ((k32 * 2 + g2) * 2 + hi) ^ (r & 7);
                    const f16x8 vf = *(const f16x8*)&Vb[r * 64 + c * 8];
                    O[d32][0] = __builtin_amdgcn_mfma_f32_32x32x16_f16(vf, pb[g2][0], O[d32][0], 0, 0, 0);
                    O[d32][1] = __builtin_amdgcn_mfma_f32_32x32x16_f16(vf, pb[g2][1], O[d32][1], 0, 0, 0);
                }
            }
        }

        if (t < NP / 64 - 1) stage_write(cur ^ 1);
        cur ^= 1;
    }

    // ---- epilogue: rowsum across hi-halves, normalize, write combT ----
    rs[0] += __shfl_xor(rs[0], 32);
    rs[1] += __shfl_xor(rs[1], 32);
    const float inv[2] = {1.0f / rs[0], 1.0f / rs[1]};
    #pragma unroll
    for (int q32 = 0; q32 < 2; ++q32) {
        const int n = qbase + q32 * 32 + l31;
        #pragma unroll
        for (int d32 = 0; d32 < 4; ++d32)
            #pragma unroll
            for (int tq = 0; tq < 4; ++tq) {
                f16 o4[4];
                #pragma unroll
                for (int jj = 0; jj < 4; ++jj)
                    o4[jj] = (f16)(O[d32][q32][tq * 4 + jj] * inv[q32]);
                *(f16x4*)&combT[((size_t)b * NP + n) * OUTC + dir * EMB + d32 * 32 + tq * 8 + hi * 4] =
                    *(const f16x4*)o4;
            }
    }
}

// =======================================================================
// Kernel 3: output projection GEMM (MFMA) + BN + ReLU, fp32 out.
// =======================================================================
__global__ __launch_bounds__(256) void proj_out_kernel(
    const f16* __restrict__ combT, const float* __restrict__ Wp,
    const float* __restrict__ G, const float* __restrict__ Be,
    const float* __restrict__ Mu, const float* __restrict__ Va,
    float* __restrict__ out)
{
    const int m0 = blockIdx.x * 128;
    const int o0 = blockIdx.y * 128;
    const int b  = blockIdx.z;
    const int tid = threadIdx.x;
    const int w = tid >> 6, lane = tid & 63, quad = lane >> 4, lr = lane & 15;

    __shared__ __align__(16) f16 smem[128 * 72 * 2];
    f16* Al = smem;
    f16* Bl = smem + 128 * 72;

    f32x4 acc[2][8];
    #pragma unroll
    for (int mi = 0; mi < 2; ++mi)
        #pragma unroll
        for (int ni = 0; ni < 8; ++ni) acc[mi][ni] = (f32x4){0.f, 0.f, 0.f, 0.f};

    for (int kt = 0; kt < 4; ++kt) {
        const int kc0 = kt * 64;
        __syncthreads();
        #pragma unroll
        for (int i = 0; i < 4; ++i) {     // A tile: f16 straight copy
            const int s2 = i * 256 + tid;
            const int n = s2 >> 3, cg = s2 & 7;
            *(f16x8*)&Al[n * 72 + cg * 8] =
                *(const f16x8*)&combT[((size_t)b * NP + m0 + n) * OUTC + kc0 + cg * 8];
        }
        for (int s2 = tid; s2 < 1024; s2 += 256) {  // B tile: fp32 -> f16
            const int d = s2 >> 3, cg = s2 & 7;
            f16 tmp[8];
            #pragma unroll
            for (int jj = 0; jj < 8; ++jj)
                tmp[jj] = (f16)Wp[(size_t)(o0 + d) * OUTC + kc0 + cg * 8 + jj];
            *(f16x8*)&Bl[d * 72 + cg * 8] = *(const f16x8*)tmp;
        }
        __syncthreads();
        #pragma unroll
        for (int ks = 0; ks < 2; ++ks) {
            f16x8 af[2], bfr[8];
            #pragma unroll
            for (int mi = 0; mi < 2; ++mi)
                af[mi] = *(const f16x8*)&Al[(w * 32 + mi * 16 + lr) * 72 + ks * 32 + quad * 8];
            #pragma unroll
            for (int ni = 0; ni < 8; ++ni)
                bfr[ni] = *(const f16x8*)&Bl[(ni * 16 + lr) * 72 + ks * 32 + quad * 8];
            #pragma unroll
            for (int mi = 0; mi < 2; ++mi)
                #pragma unroll
                for (int ni = 0; ni < 8; ++ni)
                    acc[mi][ni] = __builtin_amdgcn_mfma_f32_16x16x32_f16(
                        af[mi], bfr[ni], acc[mi][ni], 0, 0, 0);
        }
    }

    __syncthreads();
    f16* T = smem;   // [128 o][136]
    #pragma unroll
    for (int ni = 0; ni < 8; ++ni) {
        const int o = o0 + ni * 16 + lr;
        const float iv = G[o] * rsqrtf(Va[o] + BN_EPS);
        const float sh = Be[o] - Mu[o] * iv;
        #pragma unroll
        for (int mi = 0; mi < 2; ++mi)
            #pragma unroll
            for (int r = 0; r < 4; ++r)
                T[(ni * 16 + lr) * 136 + w * 32 + mi * 16 + quad * 4 + r] =
                    (f16)fmaxf(acc[mi][ni][r] * iv + sh, 0.f);
    }
    __syncthreads();
    for (int s2 = tid; s2 < 2048; s2 += 256) {
        const int o = s2 >> 4, n8 = (s2 & 15) * 8;
        const f16x8 v = *(const f16x8*)&T[o * 136 + n8];
        const size_t off = ((size_t)b * OUTC + o0 + o) * NP + m0 + n8;
        #pragma unroll
        for (int k = 0; k < 8; ++k) out[off + k] = (float)v[k];
    }
}

extern "C" void kernel_launch(void* const* d_in, const int* in_sizes, int n_in,
                              void* d_out, int out_size, void* d_ws, size_t ws_size,
                              hipStream_t stream) {
    const float* f_rgb   = (const float*)d_in[0];
    const float* f_pl    = (const float*)d_in[1];
    const float* w_q_rgb = (const float*)d_in[2];  const float* b_q_rgb = (const float*)d_in[3];
    const float* w_k_pl  = (const float*)d_in[4];  const float* b_k_pl  = (const float*)d_in[5];
    const float* w_v_pl  = (const float*)d_in[6];  const float* b_v_pl  = (const float*)d_in[7];
    const float* w_q_pl  = (const float*)d_in[8];  const float* b_q_pl  = (const float*)d_in[9];
    const float* w_k_rgb = (const float*)d_in[10]; const float* b_k_rgb = (const float*)d_in[11];
    const float* w_v_rgb = (const float*)d_in[12]; const float* b_v_rgb = (const float*)d_in[13];
    const float* w_proj  = (const float*)d_in[14];
    const float* bn_g    = (const float*)d_in[15]; const float* bn_b = (const float*)d_in[16];
    const float* bn_m    = (const float*)d_in[17]; const float* bn_v = (const float*)d_in[18];

    // ws (halves): Qt | Kt | Vn | combT  = 4 * TSZ = 67.1 MB
    f16* Qt    = (f16*)d_ws;
    f16* Kt    = Qt + TSZ;
    f16* Vn    = Kt + TSZ;
    f16* combT = Vn + TSZ;

    proj_all_kernel<<<dim3(32, 6, 8), 256, 0, stream>>>(
        f_rgb, f_pl,
        w_q_rgb, b_q_rgb, w_k_rgb, b_k_rgb, w_v_rgb, b_v_rgb,
        w_q_pl,  b_q_pl,  w_k_pl,  b_k_pl,  w_v_pl,  b_v_pl,
        Qt, Kt, Vn);

    attn_kernel<<<256, 256, 0, stream>>>(Qt, Kt, Vn, combT);

    proj_out_kernel<<<dim3(32, 2, 8), 256, 0, stream>>>(
        combT, w_proj, bn_g, bn_b, bn_m, bn_v, (float*)d_out);
}

// Round 5
// 347.455 us; speedup vs baseline: 1.0725x; 1.0725x over previous
//
#include <hip/hip_runtime.h>
#include <hip/hip_bf16.h>
#include <hip/hip_fp16.h>

typedef _Float16 f16;
typedef _Float16 f16x8 __attribute__((ext_vector_type(8)));
typedef _Float16 f16x4 __attribute__((ext_vector_type(4)));
typedef __fp16 hf16x2 __attribute__((ext_vector_type(2)));   // cvt_pkrtz return type
typedef float f32x4 __attribute__((ext_vector_type(4)));
typedef float f32x16 __attribute__((ext_vector_type(16)));

#define NP   4096   // H*W
#define NB   8      // batch
#define CINC 256    // input channels
#define EMB  128
#define OUTC 256
#define BN_EPS 1e-5f

#define DSZ  ((size_t)NB * NP * EMB)      // 4194304 halves, per-dir tensor
#define TSZ  (2 * DSZ)                    // 8388608 halves

// =======================================================================
// Kernel 1: ALL 6 input projections in one launch. grid (32, 6, 8).
//   p = blockIdx.y: 0..2 = rgb stream (q_rgb,k_rgb,v_rgb), 3..5 = pl stream.
//   j = p%3: 0 -> Q[s] ([b][n][128]) ; 1 -> K[1-s] ; 2 -> V[1-s] ([b][d][4096])
// V is written KEY-PERMUTED within each 16-key group (swap bit2<->bit3 of
// n&15) so attn's PV B-operand needs NO cross-half lane exchange: the
// 32x32 C-layout hands each lane keys {0-3,8-11}+4hi, and the permuted V
// puts exactly those keys at A-operand k-slots hi*8+j. Permutation applied
// to both contraction operands == identity on the result.
// =======================================================================
__global__ __launch_bounds__(256) void proj_all_kernel(
    const float* __restrict__ Xrgb, const float* __restrict__ Xpl,
    const float* __restrict__ w0, const float* __restrict__ b0,
    const float* __restrict__ w1, const float* __restrict__ b1,
    const float* __restrict__ w2, const float* __restrict__ b2,
    const float* __restrict__ w3, const float* __restrict__ b3,
    const float* __restrict__ w4, const float* __restrict__ b4,
    const float* __restrict__ w5, const float* __restrict__ b5,
    f16* __restrict__ Qt, f16* __restrict__ Kt, f16* __restrict__ Vn)
{
    const int m0 = blockIdx.x * 128;
    const int p  = blockIdx.y;
    const int b  = blockIdx.z;
    const int s  = (p >= 3) ? 1 : 0;
    const int j  = p - s * 3;
    const int tid = threadIdx.x;
    const int w = tid >> 6, lane = tid & 63, quad = lane >> 4, lr = lane & 15;

    const float* X  = s ? Xpl : Xrgb;
    const float* W  = p == 0 ? w0 : p == 1 ? w1 : p == 2 ? w2
                    : p == 3 ? w3 : p == 4 ? w4 : w5;
    const float* Bi = p == 0 ? b0 : p == 1 ? b1 : p == 2 ? b2
                    : p == 3 ? b3 : p == 4 ? b4 : b5;

    __shared__ __align__(16) f16 smem[128 * 72 * 2];   // 36864 B
    f16* Al = smem;             // [128 n][72]
    f16* Bl = smem + 128 * 72;  // [128 d][72]

    f32x4 acc[2][8];
    #pragma unroll
    for (int mi = 0; mi < 2; ++mi)
        #pragma unroll
        for (int ni = 0; ni < 8; ++ni) acc[mi][ni] = (f32x4){0.f, 0.f, 0.f, 0.f};

    for (int kt = 0; kt < 4; ++kt) {
        const int kc0 = kt * 64;
        __syncthreads();
        // A: X[c][n] -> Al[n][c] (transpose + convert); lanes coalesced over n
        for (int s2 = tid; s2 < 1024; s2 += 256) {
            const int n = s2 & 127, cg = s2 >> 7;
            f16 tmp[8];
            #pragma unroll
            for (int jj = 0; jj < 8; ++jj)
                tmp[jj] = (f16)X[((size_t)b * CINC + kc0 + cg * 8 + jj) * NP + m0 + n];
            *(f16x8*)&Al[n * 72 + cg * 8] = *(const f16x8*)tmp;
        }
        // B: W[d][c] contiguous fp32 -> convert
        for (int s2 = tid; s2 < 1024; s2 += 256) {
            const int d = s2 >> 3, cg = s2 & 7;
            f16 tmp[8];
            #pragma unroll
            for (int jj = 0; jj < 8; ++jj)
                tmp[jj] = (f16)W[(size_t)d * CINC + kc0 + cg * 8 + jj];
            *(f16x8*)&Bl[d * 72 + cg * 8] = *(const f16x8*)tmp;
        }
        __syncthreads();
        #pragma unroll
        for (int ks = 0; ks < 2; ++ks) {
            f16x8 af[2], bfr[8];
            #pragma unroll
            for (int mi = 0; mi < 2; ++mi)
                af[mi] = *(const f16x8*)&Al[(w * 32 + mi * 16 + lr) * 72 + ks * 32 + quad * 8];
            #pragma unroll
            for (int ni = 0; ni < 8; ++ni)
                bfr[ni] = *(const f16x8*)&Bl[(ni * 16 + lr) * 72 + ks * 32 + quad * 8];
            #pragma unroll
            for (int mi = 0; mi < 2; ++mi)
                #pragma unroll
                for (int ni = 0; ni < 8; ++ni)
                    acc[mi][ni] = __builtin_amdgcn_mfma_f32_16x16x32_f16(
                        af[mi], bfr[ni], acc[mi][ni], 0, 0, 0);
        }
    }

    float bias[8];
    #pragma unroll
    for (int ni = 0; ni < 8; ++ni) bias[ni] = Bi[ni * 16 + lr];

    if (j < 2) {
        f16* out = (j == 0) ? (Qt + (size_t)s * DSZ) : (Kt + (size_t)(1 - s) * DSZ);
        #pragma unroll
        for (int mi = 0; mi < 2; ++mi)
            #pragma unroll
            for (int ni = 0; ni < 8; ++ni)
                #pragma unroll
                for (int r = 0; r < 4; ++r) {
                    const int n = m0 + w * 32 + mi * 16 + quad * 4 + r;
                    out[((size_t)b * NP + n) * EMB + ni * 16 + lr] =
                        (f16)(acc[mi][ni][r] + bias[ni]);
                }
    } else {
        f16* outV = Vn + (size_t)(1 - s) * DSZ;
        __syncthreads();
        f16* T = smem;                        // [128 d][136]
        // key-permute: within each 16-key group, swap 4-key subgroups 1<->2
        // (quad 1 <-> quad 2), i.e. position = swap(bit2,bit3) of key.
        const int quad_p = ((quad & 1) << 1) | (quad >> 1);
        #pragma unroll
        for (int mi = 0; mi < 2; ++mi)
            #pragma unroll
            for (int ni = 0; ni < 8; ++ni)
                #pragma unroll
                for (int r = 0; r < 4; ++r)
                    T[(ni * 16 + lr) * 136 + w * 32 + mi * 16 + quad_p * 4 + r] =
                        (f16)(acc[mi][ni][r] + bias[ni]);
        __syncthreads();
        for (int s2 = tid; s2 < 2048; s2 += 256) {
            const int d = s2 >> 4, n8 = (s2 & 15) * 8;
            *(f16x8*)&outV[((size_t)b * EMB + d) * NP + m0 + n8] =
                *(const f16x8*)&T[d * 136 + n8];
        }
    }
}

// =======================================================================
// Kernel 2: flash attention, 32x32x16 MFMA structure.
//  - grid 512 = 32 n-blocks x 16 (dir,b); 2 blocks/CU (the occupancy fix:
//    round-3 measured 1 wave/SIMD -> all pipes serialized, 198us).
//    bid&15 -> (dir,b): the 32 blocks sharing K/V land on one XCD.
//  - 4 waves x 32 q (1 q32/wave), 128 q/block. __launch_bounds__(256,2).
//  - S^T = mfma_32x32x16(A=K, B=Q) -> exp2 in-register -> P packed
//    straight into the PV B-operand (V is key-permuted by proj_all, so
//    each lane's C-layout keys ARE its B-operand slots: no shfl/cndmask).
//  - PV: O^T[d][q] = mfma_32x32x16(A=V[d][pos], B=P^T) -- full-rate.
//  - K/V tiles double-buffered in LDS, XOR chunk-swizzle (c ^= row&7).
//  - T14 split staging: global loads right after barrier, ds_writes after
//    compute. s_setprio(1) around MFMA clusters (T5; 2 blocks/CU -> role
//    diversity).
// =======================================================================
__global__ __launch_bounds__(256, 2) void attn_kernel(
    const f16* __restrict__ Qt, const f16* __restrict__ Kt,
    const f16* __restrict__ Vn, f16* __restrict__ combT)
{
    const int bid = blockIdx.x;
    const int g = bid & 15, dir = g >> 3, b = g & 7;
    const int n0 = (bid >> 4) * 128;
    const int tid = threadIdx.x;
    const int w = tid >> 6, lane = tid & 63;
    const int l31 = lane & 31, hi = lane >> 5;

    const f16* __restrict__ Q = Qt + ((size_t)dir * NB + b) * NP * EMB;
    const f16* __restrict__ K = Kt + ((size_t)dir * NB + b) * NP * EMB;
    const f16* __restrict__ V = Vn + ((size_t)dir * NB + b) * (size_t)EMB * NP;

    __shared__ __align__(16) f16 Kl[2][64 * 128];    // [key][d], chunk-swizzled
    __shared__ __align__(16) f16 Vl[2][128 * 64];    // [d][pos], chunk-swizzled

    const int qbase = n0 + w * 32;

    // Q B-frags: B[k=d=hi*8+j][col=q=l31], scale*log2(e) folded in.
    f16x8 qf[8];
    #pragma unroll
    for (int d16 = 0; d16 < 8; ++d16) {
        f16x8 q = *(const f16x8*)&Q[(size_t)(qbase + l31) * EMB + d16 * 16 + hi * 8];
        #pragma unroll
        for (int jj = 0; jj < 8; ++jj)
            q[jj] = q[jj] * (f16)0.12752749f;   // 128^-0.5 * log2(e)
        qf[d16] = q;
    }

    f32x16 O[4];
    #pragma unroll
    for (int d32 = 0; d32 < 4; ++d32) O[d32] = (f32x16)(0.0f);
    float rs = 0.f;

    // staging lane decomposition (constant per thread)
    const int krp = lane >> 4, kp = lane & 15;   // K: 4 rows x 16 chunks per load
    const int vrp = lane >> 3, vp = lane & 7;    // V: 8 rows x 8 chunks per load
    f16x8 stK[4], stV[4];

    auto stage_load = [&](int m0) {
        #pragma unroll
        for (int i = 0; i < 4; ++i) {
            const int r = w * 16 + i * 4 + krp;
            const int c = kp ^ (r & 7);
            stK[i] = *(const f16x8*)&K[(size_t)(m0 + r) * EMB + c * 8];
        }
        #pragma unroll
        for (int i = 0; i < 4; ++i) {
            const int r = w * 32 + i * 8 + vrp;
            const int c = vp ^ (r & 7);
            stV[i] = *(const f16x8*)&V[(size_t)r * NP + m0 + c * 8];
        }
    };
    auto stage_write = [&](int buf) {
        #pragma unroll
        for (int i = 0; i < 4; ++i) {
            const int r = w * 16 + i * 4 + krp;
            *(f16x8*)&Kl[buf][r * 128 + kp * 8] = stK[i];
        }
        #pragma unroll
        for (int i = 0; i < 4; ++i) {
            const int r = w * 32 + i * 8 + vrp;
            *(f16x8*)&Vl[buf][r * 64 + vp * 8] = stV[i];
        }
    };

    stage_load(0);
    stage_write(0);
    int cur = 0;

    for (int t = 0; t < NP / 64; ++t) {
        __syncthreads();                        // buf[cur] ready for all waves
        if (t < NP / 64 - 1) stage_load((t + 1) * 64);

        const f16* Kb = &Kl[cur][0];
        const f16* Vb = &Vl[cur][0];

        #pragma unroll
        for (int k32 = 0; k32 < 2; ++k32) {
            // ---- QK^T (swapped): S^T[key][q] for 32 keys x 32 q ----
            f32x16 s = (f32x16)(0.0f);
            __builtin_amdgcn_s_setprio(1);
            #pragma unroll
            for (int d16 = 0; d16 < 8; ++d16) {
                const int r = k32 * 32 + l31;
                const int c = (d16 * 2 + hi) ^ (r & 7);
                const f16x8 kf = *(const f16x8*)&Kb[r * 128 + c * 8];
                s = __builtin_amdgcn_mfma_f32_32x32x16_f16(kf, qf[d16], s, 0, 0, 0);
            }
            __builtin_amdgcn_s_setprio(0);

            // ---- exp2 + rowsum + pack P into PV B-frags (no exchange) ----
            // C-layout: col=q=l31, key=(i&3)+8*(i>>2)+4*hi. This lane's
            // e[g2*8 + 0..7] are exactly the keys the PV A-operand
            // (key-permuted V) expects at k-slots hi*8 + 0..7.
            float e[16];
            #pragma unroll
            for (int i = 0; i < 16; ++i) e[i] = __builtin_amdgcn_exp2f(s[i]);
            float sum = 0.f;
            #pragma unroll
            for (int i = 0; i < 16; ++i) sum += e[i];
            rs += sum;
            f16x8 pb[2];   // [key16-group]
            #pragma unroll
            for (int g2 = 0; g2 < 2; ++g2) {
                union { hf16x2 h[4]; f16x8 v; } pu;
                #pragma unroll
                for (int t2 = 0; t2 < 4; ++t2)
                    pu.h[t2] = __builtin_amdgcn_cvt_pkrtz(e[g2 * 8 + t2 * 2],
                                                          e[g2 * 8 + t2 * 2 + 1]);
                pb[g2] = pu.v;
            }

            // ---- PV: O^T[d][q] += V[d][pos] . P^T[pos][q] (full-rate) ----
            __builtin_amdgcn_s_setprio(1);
            #pragma unroll
            for (int g2 = 0; g2 < 2; ++g2) {
                #pragma unroll
                for (int d32 = 0; d32 < 4; ++d32) {
                    const int r = d32 * 32 + l31;
                    const int c = (k32 * 4 + g2 * 2 + hi) ^ (r & 7);
                    const f16x8 vf = *(const f16x8*)&Vb[r * 64 + c * 8];
                    O[d32] = __builtin_amdgcn_mfma_f32_32x32x16_f16(vf, pb[g2], O[d32], 0, 0, 0);
                }
            }
            __builtin_amdgcn_s_setprio(0);
        }

        if (t < NP / 64 - 1) stage_write(cur ^ 1);
        cur ^= 1;
    }

    // ---- epilogue: rowsum across hi-halves, normalize, write combT ----
    rs += __shfl_xor(rs, 32);
    const float inv = 1.0f / rs;
    const int n = qbase + l31;
    #pragma unroll
    for (int d32 = 0; d32 < 4; ++d32)
        #pragma unroll
        for (int tq = 0; tq < 4; ++tq) {
            f16 o4[4];
            #pragma unroll
            for (int jj = 0; jj < 4; ++jj)
                o4[jj] = (f16)(O[d32][tq * 4 + jj] * inv);
            *(f16x4*)&combT[((size_t)b * NP + n) * OUTC + dir * EMB + d32 * 32 + tq * 8 + hi * 4] =
                *(const f16x4*)o4;
        }
}

// =======================================================================
// Kernel 3: output projection GEMM (MFMA) + BN + ReLU, fp32 out.
// =======================================================================
__global__ __launch_bounds__(256) void proj_out_kernel(
    const f16* __restrict__ combT, const float* __restrict__ Wp,
    const float* __restrict__ G, const float* __restrict__ Be,
    const float* __restrict__ Mu, const float* __restrict__ Va,
    float* __restrict__ out)
{
    const int m0 = blockIdx.x * 128;
    const int o0 = blockIdx.y * 128;
    const int b  = blockIdx.z;
    const int tid = threadIdx.x;
    const int w = tid >> 6, lane = tid & 63, quad = lane >> 4, lr = lane & 15;

    __shared__ __align__(16) f16 smem[128 * 72 * 2];
    f16* Al = smem;
    f16* Bl = smem + 128 * 72;

    f32x4 acc[2][8];
    #pragma unroll
    for (int mi = 0; mi < 2; ++mi)
        #pragma unroll
        for (int ni = 0; ni < 8; ++ni) acc[mi][ni] = (f32x4){0.f, 0.f, 0.f, 0.f};

    for (int kt = 0; kt < 4; ++kt) {
        const int kc0 = kt * 64;
        __syncthreads();
        #pragma unroll
        for (int i = 0; i < 4; ++i) {     // A tile: f16 straight copy
            const int s2 = i * 256 + tid;
            const int n = s2 >> 3, cg = s2 & 7;
            *(f16x8*)&Al[n * 72 + cg * 8] =
                *(const f16x8*)&combT[((size_t)b * NP + m0 + n) * OUTC + kc0 + cg * 8];
        }
        for (int s2 = tid; s2 < 1024; s2 += 256) {  // B tile: fp32 -> f16
            const int d = s2 >> 3, cg = s2 & 7;
            f16 tmp[8];
            #pragma unroll
            for (int jj = 0; jj < 8; ++jj)
                tmp[jj] = (f16)Wp[(size_t)(o0 + d) * OUTC + kc0 + cg * 8 + jj];
            *(f16x8*)&Bl[d * 72 + cg * 8] = *(const f16x8*)tmp;
        }
        __syncthreads();
        #pragma unroll
        for (int ks = 0; ks < 2; ++ks) {
            f16x8 af[2], bfr[8];
            #pragma unroll
            for (int mi = 0; mi < 2; ++mi)
                af[mi] = *(const f16x8*)&Al[(w * 32 + mi * 16 + lr) * 72 + ks * 32 + quad * 8];
            #pragma unroll
            for (int ni = 0; ni < 8; ++ni)
                bfr[ni] = *(const f16x8*)&Bl[(ni * 16 + lr) * 72 + ks * 32 + quad * 8];
            #pragma unroll
            for (int mi = 0; mi < 2; ++mi)
                #pragma unroll
                for (int ni = 0; ni < 8; ++ni)
                    acc[mi][ni] = __builtin_amdgcn_mfma_f32_16x16x32_f16(
                        af[mi], bfr[ni], acc[mi][ni], 0, 0, 0);
        }
    }

    __syncthreads();
    f16* T = smem;   // [128 o][136]
    #pragma unroll
    for (int ni = 0; ni < 8; ++ni) {
        const int o = o0 + ni * 16 + lr;
        const float iv = G[o] * rsqrtf(Va[o] + BN_EPS);
        const float sh = Be[o] - Mu[o] * iv;
        #pragma unroll
        for (int mi = 0; mi < 2; ++mi)
            #pragma unroll
            for (int r = 0; r < 4; ++r)
                T[(ni * 16 + lr) * 136 + w * 32 + mi * 16 + quad * 4 + r] =
                    (f16)fmaxf(acc[mi][ni][r] * iv + sh, 0.f);
    }
    __syncthreads();
    for (int s2 = tid; s2 < 2048; s2 += 256) {
        const int o = s2 >> 4, n8 = (s2 & 15) * 8;
        const f16x8 v = *(const f16x8*)&T[o * 136 + n8];
        const size_t off = ((size_t)b * OUTC + o0 + o) * NP + m0 + n8;
        #pragma unroll
        for (int k = 0; k < 8; ++k) out[off + k] = (float)v[k];
    }
}

extern "C" void kernel_launch(void* const* d_in, const int* in_sizes, int n_in,
                              void* d_out, int out_size, void* d_ws, size_t ws_size,
                              hipStream_t stream) {
    const float* f_rgb   = (const float*)d_in[0];
    const float* f_pl    = (const float*)d_in[1];
    const float* w_q_rgb = (const float*)d_in[2];  const float* b_q_rgb = (const float*)d_in[3];
    const float* w_k_pl  = (const float*)d_in[4];  const float* b_k_pl  = (const float*)d_in[5];
    const float* w_v_pl  = (const float*)d_in[6];  const float* b_v_pl  = (const float*)d_in[7];
    const float* w_q_pl  = (const float*)d_in[8];  const float* b_q_pl  = (const float*)d_in[9];
    const float* w_k_rgb = (const float*)d_in[10]; const float* b_k_rgb = (const float*)d_in[11];
    const float* w_v_rgb = (const float*)d_in[12]; const float* b_v_rgb = (const float*)d_in[13];
    const float* w_proj  = (const float*)d_in[14];
    const float* bn_g    = (const float*)d_in[15]; const float* bn_b = (const float*)d_in[16];
    const float* bn_m    = (const float*)d_in[17]; const float* bn_v = (const float*)d_in[18];

    // ws (halves): Qt | Kt | Vn | combT  = 4 * TSZ = 67.1 MB
    f16* Qt    = (f16*)d_ws;
    f16* Kt    = Qt + TSZ;
    f16* Vn    = Kt + TSZ;
    f16* combT = Vn + TSZ;

    proj_all_kernel<<<dim3(32, 6, 8), 256, 0, stream>>>(
        f_rgb, f_pl,
        w_q_rgb, b_q_rgb, w_k_rgb, b_k_rgb, w_v_rgb, b_v_rgb,
        w_q_pl,  b_q_pl,  w_k_pl,  b_k_pl,  w_v_pl,  b_v_pl,
        Qt, Kt, Vn);

    attn_kernel<<<512, 256, 0, stream>>>(Qt, Kt, Vn, combT);

    proj_out_kernel<<<dim3(32, 2, 8), 256, 0, stream>>>(
        combT, w_proj, bn_g, bn_b, bn_m, bn_v, (float*)d_out);
}